// Round 13
// baseline (381.745 us; speedup 1.0000x reference)
//
#include <hip/hip_runtime.h>
#include <cfloat>

#define NROWS 131072
#define DIM 256
#define KCODES 512
#define DECAYF 0.99f
#define OMDECAYF 0.01f
#define EPSF 1e-5f
#define BATCHF 32.0f

#define CHUNK 128
#define ROWMASK 0x1FFFF

// ---- MFMA argmin geometry ----
#define BMW 16                // rows per wave (RT=1, spill-free)
#define NWAVE 8               // waves per block
#define BMB (NWAVE * BMW)     // 128 rows per block
#define PLANE_STRIDE (KCODES * DIM)      // halves per cb plane
#define PLANE_BYTES (PLANE_STRIDE * 2)   // 262144
#define PC2 64                // codes per piece (4 tiles of 16) -> 8 barriers
#define NPIECE (KCODES / PC2) // 8
#define PIECE_H_BYTES 32768   // one plane's bytes per piece (4 tiles x 8KB)
#define SBUF_HALF 65536       // LDS bytes per buffer (both planes, 4 tiles)

typedef __attribute__((ext_vector_type(8))) _Float16 half8;  // 8 f16 = 4 VGPR
typedef __attribute__((ext_vector_type(4))) float f32x4;

// ---------------- ws layout (bytes) ----------------
// 0      : cnorm       512 f
// 2048   : counts      512 i   (zeroed by cnorm_kernel)
// 4096   : loss_acc    1 f     (zeroed by cnorm_kernel)
// 6144   : off         512 i   (zeroed by cnorm_kernel; scatter reservation)
// 12288  : enc_int     131072 i
// 536576 : rowlist 131072 i  OVERLAID with fp16 planes (512 KB):
//          cnorm writes planes -> argmin reads them -> (planes dead) ->
//          scatter writes rowlist -> chunk_sum reads rowlist. Stream-ordered.

// async global->LDS, 16B per lane (dest = wave-uniform base + lane*16)
__device__ __forceinline__ void gload_lds16(const void* g, void* l) {
  __builtin_amdgcn_global_load_lds(
      (const __attribute__((address_space(1))) unsigned int*)g,
      (__attribute__((address_space(3))) unsigned int*)l, 16, 0, 0);
}

// cnorm + init e_new with decay*e_i + emit 2-way fp16 split planes of cb in
// MFMA B-FRAGMENT ORDER + zero counts/off/loss (replaces the memset dispatch).
// plane[((tile16*8 + kc)*64 + lane)*8 + j] where for code k, dim t:
// tile16=k>>4, lane=((t>>3)&3)*16 + (k&15), kc=t>>5, j=t&7.
__global__ __launch_bounds__(256) void cnorm_kernel(const float* __restrict__ cb,
                                                    const float* __restrict__ e_i,
                                                    float* __restrict__ cnorm,
                                                    float* __restrict__ en_out,
                                                    unsigned short* __restrict__ planes,
                                                    int* __restrict__ counts,
                                                    int* __restrict__ off,
                                                    float* __restrict__ loss_acc) {
  int k = blockIdx.x;
  int t = threadIdx.x;
  if (t == 0) {
    counts[k] = 0;
    off[k] = 0;
    if (k == 0) loss_acc[0] = 0.f;
  }
  size_t idx = (size_t)k * DIM + t;
  float v = cb[idx];
  en_out[idx] = DECAYF * e_i[idx];
  _Float16 h = (_Float16)v;           // RNE
  float r1 = v - (float)h;            // exact
  _Float16 m = (_Float16)r1;          // RNE
  unsigned short hb, mb;
  __builtin_memcpy(&hb, &h, 2);
  __builtin_memcpy(&mb, &m, 2);
  int tile = k >> 4, cl = k & 15;
  int kc = t >> 5, lk = (t >> 3) & 3, j = t & 7;
  size_t faddr = ((size_t)((tile * 8 + kc) * 64 + lk * 16 + cl)) * 8 + j;
  planes[faddr] = hb;                   // plane h
  planes[PLANE_STRIDE + faddr] = mb;    // plane m
  float s = v * v;
  for (int o = 32; o > 0; o >>= 1) s += __shfl_down(s, o);
  __shared__ float p[4];
  if ((t & 63) == 0) p[t >> 6] = s;
  __syncthreads();
  if (t == 0) cnorm[k] = (p[0] + p[1]) + (p[2] + p[3]);
}

// MFMA distance-GEMM + argmin + histogram + FUSED code gather/write + loss.
// PC2=64: 4 code-tiles per piece -> 8 barriers (r12's 16 gave +10us over 32;
// continuing the one lever that works). LDS 133 KB -> 1 block/CU (8 waves).
// Per piece: 96 MFMA (~3.7K cyc) vs 64KB stage (~1.2K cyc) -> stage hidden;
// LDS-read 512KB/CU/piece is the floor (~80us over the kernel).
// Plain __syncthreads per piece: r11 proved hand vmcnt/sched_barrier grafts
// regress -- let the compiler schedule.
__global__ __launch_bounds__(512, 2) void argmin_kernel(
    const float* __restrict__ z, const unsigned short* __restrict__ planes,
    const float* __restrict__ cnorm, const float* __restrict__ cb,
    int* __restrict__ enc_int, float* __restrict__ enc_out,
    int* __restrict__ counts, float* __restrict__ code_out,
    float* __restrict__ loss_acc) {
  __shared__ __align__(16) unsigned char sbuf[2 * SBUF_HALF];  // 128 KiB
  __shared__ float cn_s[KCODES];
  __shared__ int hist[KCODES];
  __shared__ int sm_enc[BMB];
  __shared__ float lds_loss;

  const int tid = threadIdx.x;
  const int w = tid >> 6;   // wave 0..7
  const int l = tid & 63;
  const int lc = l & 15;   // fragment row/col index
  const int lk = l >> 4;   // k-group (0..3)

  hist[tid] = 0;
  cn_s[tid] = cnorm[tid];
  if (tid == 0) lds_loss = 0.f;

  // ---- load this wave's 16 z-rows into register fragments (2 fp16 splits) ----
  // A-frag: lane holds row (l&15), k = (l>>4)*8 + j.  64 VGPRs of fragments.
  half8 a_h[8], a_m[8];
  float zn = 0.f;
  {
    int row = blockIdx.x * BMB + w * BMW + lc;
    const float* zr = z + (size_t)row * DIM;
#pragma unroll
    for (int ch = 0; ch < 8; ++ch) {
      float4 v0 = *(const float4*)&zr[ch * 32 + lk * 8];
      float4 v1 = *(const float4*)&zr[ch * 32 + lk * 8 + 4];
      float vv[8] = {v0.x, v0.y, v0.z, v0.w, v1.x, v1.y, v1.z, v1.w};
      half8 hh, mm;
#pragma unroll
      for (int j = 0; j < 8; ++j) {
        float f = vv[j];
        zn += f * f;
        _Float16 hb = (_Float16)f;     // RNE
        float r1 = f - (float)hb;      // exact
        hh[j] = hb;
        mm[j] = (_Float16)r1;          // RNE
      }
      a_h[ch] = hh; a_m[ch] = mm;
    }
  }
  zn += __shfl_xor(zn, 16);
  zn += __shfl_xor(zn, 32);   // every lane now holds znorm of row lc

  float minv[4];
  int mini[4];
#pragma unroll
  for (int q = 0; q < 4; ++q) { minv[q] = FLT_MAX; mini[q] = 0; }

  const unsigned char* gplanes = (const unsigned char*)planes;

  // stage(piece p -> buffer b): 64 chunks of 1KB; wave w takes chunks 8w..8w+7.
  // waves 0-3 -> h plane (chunks 0..31); waves 4-7 -> m plane (32..63): uniform.
  // LDS image per buffer: [h tiles 0..3, 8K each][m tiles 0..3, 8K each].
#define STAGE(p, b)                                                              \
  {                                                                              \
    const unsigned char* gh = gplanes + (size_t)(p) * PIECE_H_BYTES;             \
    unsigned char* lb = &sbuf[(b) * SBUF_HALF];                                  \
    _Pragma("unroll")                                                            \
    for (int q = 0; q < 8; ++q) {                                                \
      int c = w * 8 + q;                                                         \
      const unsigned char* g = (w < 4)                                           \
          ? gh + c * 1024 + l * 16                                               \
          : gh + PLANE_BYTES + (c - 32) * 1024 + l * 16;                         \
      gload_lds16(g, lb + c * 1024);                                             \
    }                                                                            \
  }

  STAGE(0, 0);
  __syncthreads();  // drains vmcnt (stage landed) + makes cn_s/hist/lds_loss visible

#pragma unroll 1
  for (int p = 0; p < NPIECE; ++p) {
    const int cur = p & 1;
    if (p + 1 < NPIECE) STAGE(p + 1, cur ^ 1);  // async, overlaps compute below

    const int lbase = cur * SBUF_HALF;
    f32x4 acc_a0 = {0.f, 0.f, 0.f, 0.f};   // tile0: hh + hm chain
    f32x4 acc_b0 = {0.f, 0.f, 0.f, 0.f};   // tile0: mh chain
    f32x4 acc_a1 = {0.f, 0.f, 0.f, 0.f};
    f32x4 acc_b1 = {0.f, 0.f, 0.f, 0.f};
    f32x4 acc_a2 = {0.f, 0.f, 0.f, 0.f};
    f32x4 acc_b2 = {0.f, 0.f, 0.f, 0.f};
    f32x4 acc_a3 = {0.f, 0.f, 0.f, 0.f};
    f32x4 acc_b3 = {0.f, 0.f, 0.f, 0.f};
#pragma unroll
    for (int kc = 0; kc < 8; ++kc) {
      int o = lbase + kc * 1024 + l * 16;
      half8 bh0 = *(const half8*)&sbuf[o];
      half8 bh1 = *(const half8*)&sbuf[o + 8192];
      half8 bh2 = *(const half8*)&sbuf[o + 16384];
      half8 bh3 = *(const half8*)&sbuf[o + 24576];
      half8 bm0 = *(const half8*)&sbuf[o + 32768];
      half8 bm1 = *(const half8*)&sbuf[o + 40960];
      half8 bm2 = *(const half8*)&sbuf[o + 49152];
      half8 bm3 = *(const half8*)&sbuf[o + 57344];
      acc_a0 = __builtin_amdgcn_mfma_f32_16x16x32_f16(a_h[kc], bh0, acc_a0, 0, 0, 0);
      acc_a1 = __builtin_amdgcn_mfma_f32_16x16x32_f16(a_h[kc], bh1, acc_a1, 0, 0, 0);
      acc_a2 = __builtin_amdgcn_mfma_f32_16x16x32_f16(a_h[kc], bh2, acc_a2, 0, 0, 0);
      acc_a3 = __builtin_amdgcn_mfma_f32_16x16x32_f16(a_h[kc], bh3, acc_a3, 0, 0, 0);
      acc_b0 = __builtin_amdgcn_mfma_f32_16x16x32_f16(a_m[kc], bh0, acc_b0, 0, 0, 0);
      acc_b1 = __builtin_amdgcn_mfma_f32_16x16x32_f16(a_m[kc], bh1, acc_b1, 0, 0, 0);
      acc_b2 = __builtin_amdgcn_mfma_f32_16x16x32_f16(a_m[kc], bh2, acc_b2, 0, 0, 0);
      acc_b3 = __builtin_amdgcn_mfma_f32_16x16x32_f16(a_m[kc], bh3, acc_b3, 0, 0, 0);
      acc_a0 = __builtin_amdgcn_mfma_f32_16x16x32_f16(a_h[kc], bm0, acc_a0, 0, 0, 0);
      acc_a1 = __builtin_amdgcn_mfma_f32_16x16x32_f16(a_h[kc], bm1, acc_a1, 0, 0, 0);
      acc_a2 = __builtin_amdgcn_mfma_f32_16x16x32_f16(a_h[kc], bm2, acc_a2, 0, 0, 0);
      acc_a3 = __builtin_amdgcn_mfma_f32_16x16x32_f16(a_h[kc], bm3, acc_a3, 0, 0, 0);
    }
    // C layout: col = lane&15 (code), row = (lane>>4)*4 + q
    // tiles visited in ascending code order (t=0..3) -> first-min tie-break holds
    {
      int codeb = p * PC2 + lc;
      float cn0 = cn_s[codeb];
      float cn1 = cn_s[codeb + 16];
      float cn2 = cn_s[codeb + 32];
      float cn3 = cn_s[codeb + 48];
#pragma unroll
      for (int q = 0; q < 4; ++q) {
        float s0 = cn0 - 2.f * (acc_a0[q] + acc_b0[q]);
        if (s0 < minv[q]) { minv[q] = s0; mini[q] = codeb; }
        float s1 = cn1 - 2.f * (acc_a1[q] + acc_b1[q]);
        if (s1 < minv[q]) { minv[q] = s1; mini[q] = codeb + 16; }
        float s2 = cn2 - 2.f * (acc_a2[q] + acc_b2[q]);
        if (s2 < minv[q]) { minv[q] = s2; mini[q] = codeb + 32; }
        float s3 = cn3 - 2.f * (acc_a3[q] + acc_b3[q]);
        if (s3 < minv[q]) { minv[q] = s3; mini[q] = codeb + 48; }
      }
    }
    __syncthreads();  // dbuf handshake
  }
#undef STAGE

  // tie-break: codes visited ascending within a lane; strict < keeps first.

  // ---- cross-lane argmin + enc/hist/loss epilogue ----
  float lsum = 0.f;
#pragma unroll
  for (int q = 0; q < 4; ++q) {
    float v = minv[q];
    int idx = mini[q];
    for (int o = 1; o < 16; o <<= 1) {
      float ov = __shfl_xor(v, o);
      int oi = __shfl_xor(idx, o);
      if (ov < v || (ov == v && oi < idx)) { v = ov; idx = oi; }  // first-min wins
    }
    float znq = __shfl(zn, lk * 4 + q);  // znorm of row (lk*4+q)
    if (lc == 0) {
      int rloc = w * BMW + lk * 4 + q;
      int row = blockIdx.x * BMB + rloc;
      enc_int[row] = idx;
      enc_out[row] = (float)idx;
      sm_enc[rloc] = idx;
      atomicAdd(&hist[idx], 1);
      lsum += znq + v;                   // ||z||^2 + (||c||^2 - 2 dot)
    }
  }
  {
    float val = (lc == 0) ? lsum : 0.f;
    val += __shfl_xor(val, 16);
    val += __shfl_xor(val, 32);
    if (l == 0) atomicAdd(&lds_loss, val);
  }
  __syncthreads();  // sm_enc + hist + lds_loss complete

  // ---- fused code gather/write: 128 rows x 64 float4 = 8192 float4 ----
  {
    const float4* cb4 = (const float4*)cb;
    float4* out4 = (float4*)code_out;
    int base = blockIdx.x * (BMB * (DIM / 4));
#pragma unroll
    for (int it = 0; it < 16; ++it) {
      int idx = it * 512 + tid;
      int k = sm_enc[idx >> 6];
      out4[base + idx] = cb4[k * (DIM / 4) + (idx & 63)];
    }
  }

  {
    int h0 = hist[tid];
    if (h0) atomicAdd(&counts[tid], h0);
  }
  if (tid == 0) atomicAdd(loss_acc, lds_loss);
}

// Counting-sort scatter with IN-BLOCK prefix sum (replaces scan_kernel).
__global__ __launch_bounds__(256) void scatter_kernel(
    const int* __restrict__ enc, const int* __restrict__ counts,
    int* __restrict__ off, int* __restrict__ rowlist) {
  __shared__ int lcnt[KCODES];
  __shared__ int lbase[KCODES];
  __shared__ int pref[KCODES];
  int tid = threadIdx.x;
  int row = blockIdx.x * 256 + tid;
  lcnt[tid] = 0;
  lcnt[tid + 256] = 0;
  pref[tid] = counts[tid];
  pref[tid + 256] = counts[tid + 256];
  __syncthreads();
  int k = enc[row];
  int p = atomicAdd(&lcnt[k], 1);
  for (int o = 1; o < KCODES; o <<= 1) {
    int v0 = (tid >= o) ? pref[tid - o] : 0;
    int v1 = (tid + 256 >= o) ? pref[tid + 256 - o] : 0;
    __syncthreads();
    pref[tid] += v0;
    pref[tid + 256] += v1;
    __syncthreads();
  }
  int c0 = lcnt[tid];
  if (c0) lbase[tid] = (pref[tid] - counts[tid]) + atomicAdd(&off[tid], c0);
  int c1 = lcnt[tid + 256];
  if (c1) lbase[tid + 256] = (pref[tid + 256] - counts[tid + 256]) + atomicAdd(&off[tid + 256], c1);
  __syncthreads();
  rowlist[lbase[k] + p] = (k << 17) | row;
}

// Load-balanced segmented sum over sorted rowlist: 128 rows per block,
// run-length accumulate in registers, one atomicAdd per run per dim.
__global__ __launch_bounds__(256) void chunk_sum_kernel(
    const float* __restrict__ z, const int* __restrict__ rowlist,
    float* __restrict__ en_out) {
  __shared__ int rl[CHUNK];
  int tid = threadIdx.x;
  int d = tid;
  if (tid < CHUNK) rl[tid] = rowlist[blockIdx.x * CHUNK + tid];
  __syncthreads();
  int cur = rl[0] >> 17;
  float s = 0.f;
  for (int i = 0; i < CHUNK; i += 4) {
    int p0 = rl[i + 0], p1 = rl[i + 1], p2 = rl[i + 2], p3 = rl[i + 3];
    float v0 = z[(size_t)(p0 & ROWMASK) * DIM + d];
    float v1 = z[(size_t)(p1 & ROWMASK) * DIM + d];
    float v2 = z[(size_t)(p2 & ROWMASK) * DIM + d];
    float v3 = z[(size_t)(p3 & ROWMASK) * DIM + d];
    int k;
    k = p0 >> 17;
    if (k != cur) { atomicAdd(&en_out[(size_t)cur * DIM + d], OMDECAYF * s); s = 0.f; cur = k; }
    s += v0;
    k = p1 >> 17;
    if (k != cur) { atomicAdd(&en_out[(size_t)cur * DIM + d], OMDECAYF * s); s = 0.f; cur = k; }
    s += v1;
    k = p2 >> 17;
    if (k != cur) { atomicAdd(&en_out[(size_t)cur * DIM + d], OMDECAYF * s); s = 0.f; cur = k; }
    s += v2;
    k = p3 >> 17;
    if (k != cur) { atomicAdd(&en_out[(size_t)cur * DIM + d], OMDECAYF * s); s = 0.f; cur = k; }
    s += v3;
  }
  atomicAdd(&en_out[(size_t)cur * DIM + d], OMDECAYF * s);
}

// n_new from counts + cbn = e_new/n_new + loss finalize
__global__ __launch_bounds__(256) void finalize_kernel(
    const float* __restrict__ en, const int* __restrict__ counts,
    const float* __restrict__ n_i, float* __restrict__ nn_out,
    float* __restrict__ cbn_out, const float* __restrict__ loss_acc,
    float* __restrict__ loss_out) {
  int k = blockIdx.x;
  int d = threadIdx.x;
  float nn = DECAYF * n_i[k] + OMDECAYF * (float)counts[k];
  nn = (nn + EPSF) / (BATCHF + (float)KCODES * EPSF) * BATCHF;
  if (d == 0) nn_out[k] = nn;
  size_t idx = (size_t)k * DIM + d;
  cbn_out[idx] = en[idx] / nn;
  if (k == 0 && d == 0) loss_out[0] = 0.25f * loss_acc[0] / 33554432.0f;
}

extern "C" void kernel_launch(void* const* d_in, const int* in_sizes, int n_in,
                              void* d_out, int out_size, void* d_ws, size_t ws_size,
                              hipStream_t stream) {
  const float* z = (const float*)d_in[0];
  const float* cb = (const float*)d_in[1];
  const float* n_i = (const float*)d_in[2];
  const float* e_i = (const float*)d_in[3];

  float* out = (float*)d_out;
  float* out_code = out;                    // 33554432
  float* out_loss = out + 33554432;         // 1
  float* out_enc = out + 33554433;          // 131072
  float* out_cbn = out + 33685505;          // 131072
  float* out_nn = out + 33816577;           // 512
  float* out_en = out + 33817089;           // 131072

  char* ws = (char*)d_ws;
  float* cnorm = (float*)(ws + 0);
  int* counts = (int*)(ws + 2048);
  float* loss_acc = (float*)(ws + 4096);
  int* off = (int*)(ws + 6144);
  int* enc_int = (int*)(ws + 12288);
  int* rowlist = (int*)(ws + 536576);
  unsigned short* planes = (unsigned short*)(ws + 536576);  // overlay (see layout)

  cnorm_kernel<<<KCODES, 256, 0, stream>>>(cb, e_i, cnorm, out_en, planes,
                                           counts, off, loss_acc);
  argmin_kernel<<<NROWS / BMB, 512, 0, stream>>>(z, planes, cnorm, cb, enc_int,
                                                 out_enc, counts, out_code, loss_acc);
  scatter_kernel<<<NROWS / 256, 256, 0, stream>>>(enc_int, counts, off, rowlist);
  chunk_sum_kernel<<<NROWS / CHUNK, 256, 0, stream>>>(z, rowlist, out_en);
  finalize_kernel<<<KCODES, 256, 0, stream>>>(out_en, counts, n_i, out_nn,
                                              out_cbn, loss_acc, out_loss);
}

// Round 14
// 351.767 us; speedup vs baseline: 1.0852x; 1.0852x over previous
//
#include <hip/hip_runtime.h>
#include <cfloat>

#define NROWS 131072
#define DIM 256
#define KCODES 512
#define DECAYF 0.99f
#define OMDECAYF 0.01f
#define EPSF 1e-5f
#define BATCHF 32.0f

#define CHUNK 128
#define ROWMASK 0x1FFFF

// ---- MFMA argmin geometry ----
#define BMW 16                // rows per wave (RT=1, spill-free)
#define NWAVE 8               // waves per block
#define BMB (NWAVE * BMW)     // 128 rows per block
#define PLANE_STRIDE (KCODES * DIM)      // halves per cb plane
#define PLANE_BYTES (PLANE_STRIDE * 2)   // 262144
#define PC2 32                // codes per piece (2 tiles of 16) -> 16 barriers
#define NPIECE (KCODES / PC2) // 16
#define PIECE_H_BYTES 16384   // one plane's bytes per piece (2 tiles x 8KB)
#define SBUF_HALF 32768       // LDS bytes per buffer (both planes, 2 tiles)

typedef __attribute__((ext_vector_type(8))) _Float16 half8;  // 8 f16 = 4 VGPR
typedef __attribute__((ext_vector_type(4))) float f32x4;

// ---------------- ws layout (bytes) ----------------
// 0      : cnorm       512 f
// 2048   : counts      512 i   (zeroed by cnorm_kernel)
// 4096   : loss_acc    1 f     (zeroed by cnorm_kernel)
// 6144   : off         512 i   (zeroed by cnorm_kernel; scatter reservation)
// 12288  : enc_int     131072 i
// 536576 : rowlist 131072 i  OVERLAID with fp16 planes (512 KB):
//          cnorm writes planes -> argmin reads them -> (planes dead) ->
//          scatter writes rowlist -> chunk_sum reads rowlist. Stream-ordered.

// async global->LDS, 16B per lane (dest = wave-uniform base + lane*16)
__device__ __forceinline__ void gload_lds16(const void* g, void* l) {
  __builtin_amdgcn_global_load_lds(
      (const __attribute__((address_space(1))) unsigned int*)g,
      (__attribute__((address_space(3))) unsigned int*)l, 16, 0, 0);
}

// cnorm + init e_new with decay*e_i + emit 2-way fp16 split planes of cb in
// MFMA B-FRAGMENT ORDER + zero counts/off/loss (replaces the memset dispatch).
// plane[((tile16*8 + kc)*64 + lane)*8 + j] where for code k, dim t:
// tile16=k>>4, lane=((t>>3)&3)*16 + (k&15), kc=t>>5, j=t&7.
__global__ __launch_bounds__(256) void cnorm_kernel(const float* __restrict__ cb,
                                                    const float* __restrict__ e_i,
                                                    float* __restrict__ cnorm,
                                                    float* __restrict__ en_out,
                                                    unsigned short* __restrict__ planes,
                                                    int* __restrict__ counts,
                                                    int* __restrict__ off,
                                                    float* __restrict__ loss_acc) {
  int k = blockIdx.x;
  int t = threadIdx.x;
  if (t == 0) {
    counts[k] = 0;
    off[k] = 0;
    if (k == 0) loss_acc[0] = 0.f;
  }
  size_t idx = (size_t)k * DIM + t;
  float v = cb[idx];
  en_out[idx] = DECAYF * e_i[idx];
  _Float16 h = (_Float16)v;           // RNE
  float r1 = v - (float)h;            // exact
  _Float16 m = (_Float16)r1;          // RNE
  unsigned short hb, mb;
  __builtin_memcpy(&hb, &h, 2);
  __builtin_memcpy(&mb, &m, 2);
  int tile = k >> 4, cl = k & 15;
  int kc = t >> 5, lk = (t >> 3) & 3, j = t & 7;
  size_t faddr = ((size_t)((tile * 8 + kc) * 64 + lk * 16 + cl)) * 8 + j;
  planes[faddr] = hb;                   // plane h
  planes[PLANE_STRIDE + faddr] = mb;    // plane m
  float s = v * v;
  for (int o = 32; o > 0; o >>= 1) s += __shfl_down(s, o);
  __shared__ float p[4];
  if ((t & 63) == 0) p[t >> 6] = s;
  __syncthreads();
  if (t == 0) cnorm[k] = (p[0] + p[1]) + (p[2] + p[3]);
}

// MFMA distance-GEMM + argmin + histogram + FUSED code gather/write + loss.
// FINAL (r12 optimum): PC2=32 -> 16 barriers, 512 threads RT=1, 2 blocks/CU.
// Family characterization: 32 barriers@2blk=160us, 16@2=150 (optimum),
// 8@1=184; RT=2 spills (unified-RF quanta), hand-vmcnt pipeline regresses
// (compiler-schedule defeat), staging VMEM not binding. Residual ~70us is
// 2-phase barrier exposure; below it requires an 8-phase co-design (new
// kernel family). Loss via ||z-c||^2 = ||z||^2 + s_min; fp16 2-way split
// dot (hh+mh+hm), dropped terms ~2^-22 rel.
__global__ __launch_bounds__(512, 4) void argmin_kernel(
    const float* __restrict__ z, const unsigned short* __restrict__ planes,
    const float* __restrict__ cnorm, const float* __restrict__ cb,
    int* __restrict__ enc_int, float* __restrict__ enc_out,
    int* __restrict__ counts, float* __restrict__ code_out,
    float* __restrict__ loss_acc) {
  __shared__ __align__(16) unsigned char sbuf[2 * SBUF_HALF];  // 64 KiB
  __shared__ float cn_s[KCODES];
  __shared__ int hist[KCODES];
  __shared__ int sm_enc[BMB];
  __shared__ float lds_loss;

  const int tid = threadIdx.x;
  const int w = tid >> 6;   // wave 0..7
  const int l = tid & 63;
  const int lc = l & 15;   // fragment row/col index
  const int lk = l >> 4;   // k-group (0..3)

  hist[tid] = 0;
  cn_s[tid] = cnorm[tid];
  if (tid == 0) lds_loss = 0.f;

  // ---- load this wave's 16 z-rows into register fragments (2 fp16 splits) ----
  // A-frag: lane holds row (l&15), k = (l>>4)*8 + j.  64 VGPRs of fragments.
  half8 a_h[8], a_m[8];
  float zn = 0.f;
  {
    int row = blockIdx.x * BMB + w * BMW + lc;
    const float* zr = z + (size_t)row * DIM;
#pragma unroll
    for (int ch = 0; ch < 8; ++ch) {
      float4 v0 = *(const float4*)&zr[ch * 32 + lk * 8];
      float4 v1 = *(const float4*)&zr[ch * 32 + lk * 8 + 4];
      float vv[8] = {v0.x, v0.y, v0.z, v0.w, v1.x, v1.y, v1.z, v1.w};
      half8 hh, mm;
#pragma unroll
      for (int j = 0; j < 8; ++j) {
        float f = vv[j];
        zn += f * f;
        _Float16 hb = (_Float16)f;     // RNE
        float r1 = f - (float)hb;      // exact
        hh[j] = hb;
        mm[j] = (_Float16)r1;          // RNE
      }
      a_h[ch] = hh; a_m[ch] = mm;
    }
  }
  zn += __shfl_xor(zn, 16);
  zn += __shfl_xor(zn, 32);   // every lane now holds znorm of row lc

  float minv[4];
  int mini[4];
#pragma unroll
  for (int q = 0; q < 4; ++q) { minv[q] = FLT_MAX; mini[q] = 0; }

  const unsigned char* gplanes = (const unsigned char*)planes;

  // stage(piece p -> buffer b): 32 chunks of 1KB; wave w takes chunks 4w..4w+3.
  // waves 0-3 -> h plane (chunks 0..15); waves 4-7 -> m plane (16..31): uniform.
  // LDS image per buffer: [h tile0 8K][h tile1 8K][m tile0 8K][m tile1 8K].
#define STAGE(p, b)                                                              \
  {                                                                              \
    const unsigned char* gh = gplanes + (size_t)(p) * PIECE_H_BYTES;             \
    unsigned char* lb = &sbuf[(b) * SBUF_HALF];                                  \
    _Pragma("unroll")                                                            \
    for (int q = 0; q < 4; ++q) {                                                \
      int c = w * 4 + q;                                                         \
      const unsigned char* g = (w < 4)                                           \
          ? gh + c * 1024 + l * 16                                               \
          : gh + PLANE_BYTES + (c - 16) * 1024 + l * 16;                         \
      gload_lds16(g, lb + c * 1024);                                             \
    }                                                                            \
  }

  STAGE(0, 0);
  __syncthreads();  // drains vmcnt (stage landed) + makes cn_s/hist/lds_loss visible

#pragma unroll 1
  for (int p = 0; p < NPIECE; ++p) {
    const int cur = p & 1;
    if (p + 1 < NPIECE) STAGE(p + 1, cur ^ 1);  // async, overlaps compute below

    const int lbase = cur * SBUF_HALF;
    f32x4 acc_a0 = {0.f, 0.f, 0.f, 0.f};   // tile0: hh + hm chain
    f32x4 acc_b0 = {0.f, 0.f, 0.f, 0.f};   // tile0: mh chain
    f32x4 acc_a1 = {0.f, 0.f, 0.f, 0.f};   // tile1: hh + hm chain
    f32x4 acc_b1 = {0.f, 0.f, 0.f, 0.f};   // tile1: mh chain
#pragma unroll
    for (int kc = 0; kc < 8; ++kc) {
      int o = lbase + kc * 1024 + l * 16;
      half8 bh0 = *(const half8*)&sbuf[o];
      half8 bh1 = *(const half8*)&sbuf[o + 8192];
      half8 bm0 = *(const half8*)&sbuf[o + 16384];
      half8 bm1 = *(const half8*)&sbuf[o + 24576];
      acc_a0 = __builtin_amdgcn_mfma_f32_16x16x32_f16(a_h[kc], bh0, acc_a0, 0, 0, 0);
      acc_a1 = __builtin_amdgcn_mfma_f32_16x16x32_f16(a_h[kc], bh1, acc_a1, 0, 0, 0);
      acc_b0 = __builtin_amdgcn_mfma_f32_16x16x32_f16(a_m[kc], bh0, acc_b0, 0, 0, 0);
      acc_b1 = __builtin_amdgcn_mfma_f32_16x16x32_f16(a_m[kc], bh1, acc_b1, 0, 0, 0);
      acc_a0 = __builtin_amdgcn_mfma_f32_16x16x32_f16(a_h[kc], bm0, acc_a0, 0, 0, 0);
      acc_a1 = __builtin_amdgcn_mfma_f32_16x16x32_f16(a_h[kc], bm1, acc_a1, 0, 0, 0);
    }
    // C layout: col = lane&15 (code), row = (lane>>4)*4 + q
    {
      int code0 = p * PC2 + lc;          // tile 2p
      int code1 = p * PC2 + 16 + lc;     // tile 2p+1
      float cn0 = cn_s[code0];
      float cn1 = cn_s[code1];
#pragma unroll
      for (int q = 0; q < 4; ++q) {
        float s0 = cn0 - 2.f * (acc_a0[q] + acc_b0[q]);
        if (s0 < minv[q]) { minv[q] = s0; mini[q] = code0; }
        float s1 = cn1 - 2.f * (acc_a1[q] + acc_b1[q]);
        if (s1 < minv[q]) { minv[q] = s1; mini[q] = code1; }
      }
    }
    __syncthreads();  // dbuf handshake
  }
#undef STAGE

  // tie-break: codes visited ascending within a lane (code0 < code1, pieces
  // ascending); strict < keeps first.

  // ---- cross-lane argmin + enc/hist/loss epilogue ----
  float lsum = 0.f;
#pragma unroll
  for (int q = 0; q < 4; ++q) {
    float v = minv[q];
    int idx = mini[q];
    for (int o = 1; o < 16; o <<= 1) {
      float ov = __shfl_xor(v, o);
      int oi = __shfl_xor(idx, o);
      if (ov < v || (ov == v && oi < idx)) { v = ov; idx = oi; }  // first-min wins
    }
    float znq = __shfl(zn, lk * 4 + q);  // znorm of row (lk*4+q)
    if (lc == 0) {
      int rloc = w * BMW + lk * 4 + q;
      int row = blockIdx.x * BMB + rloc;
      enc_int[row] = idx;
      enc_out[row] = (float)idx;
      sm_enc[rloc] = idx;
      atomicAdd(&hist[idx], 1);
      lsum += znq + v;                   // ||z||^2 + (||c||^2 - 2 dot)
    }
  }
  {
    float val = (lc == 0) ? lsum : 0.f;
    val += __shfl_xor(val, 16);
    val += __shfl_xor(val, 32);
    if (l == 0) atomicAdd(&lds_loss, val);
  }
  __syncthreads();  // sm_enc + hist + lds_loss complete

  // ---- fused code gather/write: 128 rows x 64 float4 = 8192 float4 ----
  {
    const float4* cb4 = (const float4*)cb;
    float4* out4 = (float4*)code_out;
    int base = blockIdx.x * (BMB * (DIM / 4));
#pragma unroll
    for (int it = 0; it < 16; ++it) {
      int idx = it * 512 + tid;
      int k = sm_enc[idx >> 6];
      out4[base + idx] = cb4[k * (DIM / 4) + (idx & 63)];
    }
  }

  {
    int h0 = hist[tid];
    if (h0) atomicAdd(&counts[tid], h0);
  }
  if (tid == 0) atomicAdd(loss_acc, lds_loss);
}

// Counting-sort scatter with IN-BLOCK prefix sum (replaces scan_kernel).
__global__ __launch_bounds__(256) void scatter_kernel(
    const int* __restrict__ enc, const int* __restrict__ counts,
    int* __restrict__ off, int* __restrict__ rowlist) {
  __shared__ int lcnt[KCODES];
  __shared__ int lbase[KCODES];
  __shared__ int pref[KCODES];
  int tid = threadIdx.x;
  int row = blockIdx.x * 256 + tid;
  lcnt[tid] = 0;
  lcnt[tid + 256] = 0;
  pref[tid] = counts[tid];
  pref[tid + 256] = counts[tid + 256];
  __syncthreads();
  int k = enc[row];
  int p = atomicAdd(&lcnt[k], 1);
  for (int o = 1; o < KCODES; o <<= 1) {
    int v0 = (tid >= o) ? pref[tid - o] : 0;
    int v1 = (tid + 256 >= o) ? pref[tid + 256 - o] : 0;
    __syncthreads();
    pref[tid] += v0;
    pref[tid + 256] += v1;
    __syncthreads();
  }
  int c0 = lcnt[tid];
  if (c0) lbase[tid] = (pref[tid] - counts[tid]) + atomicAdd(&off[tid], c0);
  int c1 = lcnt[tid + 256];
  if (c1) lbase[tid + 256] = (pref[tid + 256] - counts[tid + 256]) + atomicAdd(&off[tid + 256], c1);
  __syncthreads();
  rowlist[lbase[k] + p] = (k << 17) | row;
}

// Load-balanced segmented sum over sorted rowlist: 128 rows per block,
// run-length accumulate in registers, one atomicAdd per run per dim.
__global__ __launch_bounds__(256) void chunk_sum_kernel(
    const float* __restrict__ z, const int* __restrict__ rowlist,
    float* __restrict__ en_out) {
  __shared__ int rl[CHUNK];
  int tid = threadIdx.x;
  int d = tid;
  if (tid < CHUNK) rl[tid] = rowlist[blockIdx.x * CHUNK + tid];
  __syncthreads();
  int cur = rl[0] >> 17;
  float s = 0.f;
  for (int i = 0; i < CHUNK; i += 4) {
    int p0 = rl[i + 0], p1 = rl[i + 1], p2 = rl[i + 2], p3 = rl[i + 3];
    float v0 = z[(size_t)(p0 & ROWMASK) * DIM + d];
    float v1 = z[(size_t)(p1 & ROWMASK) * DIM + d];
    float v2 = z[(size_t)(p2 & ROWMASK) * DIM + d];
    float v3 = z[(size_t)(p3 & ROWMASK) * DIM + d];
    int k;
    k = p0 >> 17;
    if (k != cur) { atomicAdd(&en_out[(size_t)cur * DIM + d], OMDECAYF * s); s = 0.f; cur = k; }
    s += v0;
    k = p1 >> 17;
    if (k != cur) { atomicAdd(&en_out[(size_t)cur * DIM + d], OMDECAYF * s); s = 0.f; cur = k; }
    s += v1;
    k = p2 >> 17;
    if (k != cur) { atomicAdd(&en_out[(size_t)cur * DIM + d], OMDECAYF * s); s = 0.f; cur = k; }
    s += v2;
    k = p3 >> 17;
    if (k != cur) { atomicAdd(&en_out[(size_t)cur * DIM + d], OMDECAYF * s); s = 0.f; cur = k; }
    s += v3;
  }
  atomicAdd(&en_out[(size_t)cur * DIM + d], OMDECAYF * s);
}

// n_new from counts + cbn = e_new/n_new + loss finalize
__global__ __launch_bounds__(256) void finalize_kernel(
    const float* __restrict__ en, const int* __restrict__ counts,
    const float* __restrict__ n_i, float* __restrict__ nn_out,
    float* __restrict__ cbn_out, const float* __restrict__ loss_acc,
    float* __restrict__ loss_out) {
  int k = blockIdx.x;
  int d = threadIdx.x;
  float nn = DECAYF * n_i[k] + OMDECAYF * (float)counts[k];
  nn = (nn + EPSF) / (BATCHF + (float)KCODES * EPSF) * BATCHF;
  if (d == 0) nn_out[k] = nn;
  size_t idx = (size_t)k * DIM + d;
  cbn_out[idx] = en[idx] / nn;
  if (k == 0 && d == 0) loss_out[0] = 0.25f * loss_acc[0] / 33554432.0f;
}

extern "C" void kernel_launch(void* const* d_in, const int* in_sizes, int n_in,
                              void* d_out, int out_size, void* d_ws, size_t ws_size,
                              hipStream_t stream) {
  const float* z = (const float*)d_in[0];
  const float* cb = (const float*)d_in[1];
  const float* n_i = (const float*)d_in[2];
  const float* e_i = (const float*)d_in[3];

  float* out = (float*)d_out;
  float* out_code = out;                    // 33554432
  float* out_loss = out + 33554432;         // 1
  float* out_enc = out + 33554433;          // 131072
  float* out_cbn = out + 33685505;          // 131072
  float* out_nn = out + 33816577;           // 512
  float* out_en = out + 33817089;           // 131072

  char* ws = (char*)d_ws;
  float* cnorm = (float*)(ws + 0);
  int* counts = (int*)(ws + 2048);
  float* loss_acc = (float*)(ws + 4096);
  int* off = (int*)(ws + 6144);
  int* enc_int = (int*)(ws + 12288);
  int* rowlist = (int*)(ws + 536576);
  unsigned short* planes = (unsigned short*)(ws + 536576);  // overlay (see layout)

  cnorm_kernel<<<KCODES, 256, 0, stream>>>(cb, e_i, cnorm, out_en, planes,
                                           counts, off, loss_acc);
  argmin_kernel<<<NROWS / BMB, 512, 0, stream>>>(z, planes, cnorm, cb, enc_int,
                                                 out_enc, counts, out_code, loss_acc);
  scatter_kernel<<<NROWS / 256, 256, 0, stream>>>(enc_int, counts, off, rowlist);
  chunk_sum_kernel<<<NROWS / CHUNK, 256, 0, stream>>>(z, rowlist, out_en);
  finalize_kernel<<<KCODES, 256, 0, stream>>>(out_en, counts, n_i, out_nn,
                                              out_cbn, loss_acc, out_loss);
}